// Round 5
// baseline (281.301 us; speedup 1.0000x reference)
//
#include <hip/hip_runtime.h>

#define NROWS 262144
#define NCOLS 128
#define TPB 256
#define WPB (TPB / 64)
#define NBLOCKS (NROWS / TPB)   // 1024 blocks, one row per thread

typedef float floatx4 __attribute__((ext_vector_type(4)));

// R5: row-per-thread restructure. R3/R4 showed the old 2-rows-per-wave
// structure is DS-pipe-bound: 56 cross-lane ops per wave-pair-loop (butterfly
// max + broadcasts) serialize on the single per-CU LDS/DS unit (~90us at
// ~60cy/op), with VALU 9.5% / HBM 17% / MLP changes all neutral. Here each
// thread owns one full 512B row: lane-local streaming scan, ZERO cross-lane
// ops in the hot loop (one 6-step wave reduction at the end). Loads are
// per-thread contiguous (base + imm offsets); 64B lines reused by 4
// consecutive chunk loads via L1 (plain loads on purpose - NT would defeat
// the L1 reuse).
//
// Semantics per row (reference-exact):
//   M  = max(x[row])            (fmax tree order-independent)
//   tM = t at FIRST index achieving M (strict-> running scan)
//   cond = (argmax > 0) && (t[row][0] == 0)  ==  (x0 != M) && (t0 == 0)
//   contrib = cond ? |M * tM| : sum_c |x_c * t_c|     (|M|*tM == |M*tM|, t in {0,1})
__global__ __launch_bounds__(TPB) void biased_loss_rows(
    const float* __restrict__ x, const float* __restrict__ t,
    float* __restrict__ partial)
{
    const int row = blockIdx.x * TPB + threadIdx.x;
    const float* xr = x + (size_t)row * NCOLS;
    const float* tr = t + (size_t)row * NCOLS;

    // chunk 0 (establishes x0/t0 and seeds the scan at index 0)
    floatx4 xc = *(const floatx4*)xr;
    floatx4 tc = *(const floatx4*)tr;
    const float x0 = xc.x;
    const float t0 = tc.x;

    float M  = xc.x;
    float tM = tc.x;
    float S  = fabsf(xc.x * tc.x);

#define STEP(v, tv)                                   \
    do {                                              \
        if ((v) > M) tM = (tv);   /* cmp+cndmask */   \
        M = fmaxf(M, (v));        /* v_max       */   \
        S += fabsf((v) * (tv));                       \
    } while (0)

    STEP(xc.y, tc.y);
    STEP(xc.z, tc.z);
    STEP(xc.w, tc.w);

    #pragma unroll
    for (int j = 1; j < NCOLS / 4; ++j) {
        xc = *(const floatx4*)(xr + j * 4);
        tc = *(const floatx4*)(tr + j * 4);
        STEP(xc.x, tc.x);
        STEP(xc.y, tc.y);
        STEP(xc.z, tc.z);
        STEP(xc.w, tc.w);
    }
#undef STEP

    const bool cond = (x0 != M) && (t0 == 0.0f);
    float acc = cond ? fabsf(M) * tM : S;

    // full-wave sum (the only cross-lane work in the kernel)
    #pragma unroll
    for (int off = 32; off > 0; off >>= 1)
        acc += __shfl_xor(acc, off, 64);

    const int lane = threadIdx.x & 63;
    const int waveInBlock = threadIdx.x >> 6;
    __shared__ float smem[WPB];
    if (lane == 0) smem[waveInBlock] = acc;
    __syncthreads();
    if (threadIdx.x == 0) {
        float bsum = 0.0f;
        #pragma unroll
        for (int w = 0; w < WPB; ++w) bsum += smem[w];
        partial[blockIdx.x] = bsum;
    }
}

__global__ __launch_bounds__(256) void reduce_partials(
    const float* __restrict__ partial, float* __restrict__ out, int n)
{
    float acc = 0.0f;
    for (int i = threadIdx.x; i < n; i += 256) acc += partial[i];
    #pragma unroll
    for (int off = 32; off > 0; off >>= 1)
        acc += __shfl_xor(acc, off, 64);
    __shared__ float smem[4];
    const int lane = threadIdx.x & 63, w = threadIdx.x >> 6;
    if (lane == 0) smem[w] = acc;
    __syncthreads();
    if (threadIdx.x == 0) {
        float s = smem[0] + smem[1] + smem[2] + smem[3];
        out[0] = s / (float)((size_t)NROWS * (size_t)NCOLS);
    }
}

extern "C" void kernel_launch(void* const* d_in, const int* in_sizes, int n_in,
                              void* d_out, int out_size, void* d_ws, size_t ws_size,
                              hipStream_t stream) {
    const float* x = (const float*)d_in[0];
    const float* t = (const float*)d_in[1];
    float* partial = (float*)d_ws;  // NBLOCKS * 4 B = 4 KiB scratch

    biased_loss_rows<<<NBLOCKS, TPB, 0, stream>>>(x, t, partial);
    reduce_partials<<<1, 256, 0, stream>>>(partial, (float*)d_out, NBLOCKS);
}

// Round 6
// 277.268 us; speedup vs baseline: 1.0145x; 1.0145x over previous
//
#include <hip/hip_runtime.h>

#define NROWS 262144
#define NCOLS 128
#define TPB 256
#define WPB (TPB / 64)
#define ROWS_PER_BLOCK 32
#define NBLOCKS (NROWS / ROWS_PER_BLOCK)   // 8192
#define ROWS_PER_WAVE 8                    // each wave stages+computes its own rows

typedef float floatx4 __attribute__((ext_vector_type(4)));

// R6: global_load_lds staging. R1-R5 established the kernel is read-latency
// bound (~100us regardless of structure; warm replays with FETCH~0 equally
// slow) because the compiler never holds more than ~2-4 loads in flight
// (VGPR_Count 28-40 in every build). global_load_lds destinations are LDS,
// not VGPRs, so outstanding loads cost zero registers: each wave issues 8
// width-16 loads back-to-back (8KB in flight), ~20 waves/CU -> ~160KB/CU
// outstanding vs the ~4KB we've been getting.
//
// Waves are fully independent: each stages its own 8 rows and computes them
// (no __syncthreads in the hot path). Compute reads LDS with chunk order
// rotated by row (c = (k+row)&3): per ds_read_b128 the 64 lanes then spread
// 8 accesses/bank (optimal); unrotated, all lanes hit the same 4 banks.
//
// Exact reference semantics per row:
//   (M, jfirst, tM) = (max, FIRST argmax index, t[argmax]) via
//   (value, min-index) tie-break -- order-independent, exact.
//   cond = (jfirst > 0) && (t[row][0] == 0)
//   contrib = cond ? |M|*tM : sum_c |x_c*t_c|   (|M|*tM == |M*tM|, t in {0,1})
__global__ __launch_bounds__(TPB) void biased_loss_lds(
    const float* __restrict__ x, const float* __restrict__ t,
    float* __restrict__ partial)
{
    __shared__ float lx[ROWS_PER_BLOCK * NCOLS];   // 16 KB
    __shared__ float lt[ROWS_PER_BLOCK * NCOLS];   // 16 KB

    const int tid  = threadIdx.x;
    const int lane = tid & 63;
    const int w    = tid >> 6;

    // ---- stage: wave w stages its own 8 rows of x and t ----
    // instr j stages rows (w*8 + 2j, w*8 + 2j + 1): 1 KB per instr,
    // LDS dest = wave-uniform base + lane*16 (linear), source per-lane.
    const size_t blockRow = (size_t)blockIdx.x * ROWS_PER_BLOCK;
    #pragma unroll
    for (int j = 0; j < 4; ++j) {
        const int lr = w * ROWS_PER_WAVE + 2 * j;
        const size_t g = (blockRow + lr) * NCOLS + (size_t)lane * 4;
        __builtin_amdgcn_global_load_lds(
            (const __attribute__((address_space(1))) void*)(x + g),
            (__attribute__((address_space(3))) void*)(lx + lr * NCOLS),
            16, 0, 0);
        __builtin_amdgcn_global_load_lds(
            (const __attribute__((address_space(1))) void*)(t + g),
            (__attribute__((address_space(3))) void*)(lt + lr * NCOLS),
            16, 0, 0);
    }
    asm volatile("s_waitcnt vmcnt(0)" ::: "memory");
    __builtin_amdgcn_sched_barrier(0);

    // ---- compute: eighth-row per thread (16 cols), all from LDS ----
    const int rlocal = tid >> 3;          // 0..31  (== w*8 + (lane>>3))
    const int q      = tid & 7;           // column-segment 0..7
    const float* lxr = lx + rlocal * NCOLS + q * 16;
    const float* ltr = lt + rlocal * NCOLS + q * 16;
    const int rot = rlocal & 3;

    float M = 0.0f, tM = 0.0f, S = 0.0f, t0loc = 0.0f;
    int jfirst = 0;

    #pragma unroll
    for (int k = 0; k < 4; ++k) {
        const int c = (k + rot) & 3;                  // rotated chunk order
        const floatx4 xc = *(const floatx4*)(lxr + c * 4);
        const floatx4 tc = *(const floatx4*)(ltr + c * 4);

        // in-order scan of this chunk (first occurrence within chunk)
        float mc = xc.x; int jc = 0; float tmc = tc.x;
        if (xc.y > mc) { mc = xc.y; jc = 1; tmc = tc.y; }
        if (xc.z > mc) { mc = xc.z; jc = 2; tmc = tc.z; }
        if (xc.w > mc) { mc = xc.w; jc = 3; tmc = tc.w; }
        const int jabs = q * 16 + c * 4 + jc;

        if (k == 0) { M = mc; jfirst = jabs; tM = tmc; }
        else if (mc > M || (mc == M && jabs < jfirst)) {
            M = mc; jfirst = jabs; tM = tmc;
        }
        if (c == 0) t0loc = tc.x;                     // col q*16 (col 0 iff q==0)

        S += fabsf(xc.x * tc.x) + fabsf(xc.y * tc.y)
           + fabsf(xc.z * tc.z) + fabsf(xc.w * tc.w);
    }

    // merge across the 8 threads of this row (lanes differing in bits 0-2);
    // (value, min-index) tie-break keeps exact first-occurrence argmax
    #pragma unroll
    for (int off = 1; off <= 4; off <<= 1) {
        const float oM  = __shfl_xor(M, off, 64);
        const int   oj  = __shfl_xor(jfirst, off, 64);
        const float otM = __shfl_xor(tM, off, 64);
        if (oM > M || (oM == M && oj < jfirst)) { M = oM; jfirst = oj; tM = otM; }
        S += __shfl_xor(S, off, 64);
    }

    float acc = 0.0f;
    if (q == 0) {
        const bool cond = (jfirst > 0) && (t0loc == 0.0f);
        acc = cond ? fabsf(M) * tM : S;
    }

    // full-wave sum
    #pragma unroll
    for (int off = 32; off > 0; off >>= 1)
        acc += __shfl_xor(acc, off, 64);

    __shared__ float smem[WPB];
    if (lane == 0) smem[w] = acc;
    __syncthreads();
    if (tid == 0) {
        float bsum = 0.0f;
        #pragma unroll
        for (int i = 0; i < WPB; ++i) bsum += smem[i];
        partial[blockIdx.x] = bsum;
    }
}

__global__ __launch_bounds__(256) void reduce_partials(
    const float* __restrict__ partial, float* __restrict__ out, int n)
{
    float acc = 0.0f;
    for (int i = threadIdx.x; i < n; i += 256) acc += partial[i];
    #pragma unroll
    for (int off = 32; off > 0; off >>= 1)
        acc += __shfl_xor(acc, off, 64);
    __shared__ float smem[4];
    const int lane = threadIdx.x & 63, w = threadIdx.x >> 6;
    if (lane == 0) smem[w] = acc;
    __syncthreads();
    if (threadIdx.x == 0) {
        float s = smem[0] + smem[1] + smem[2] + smem[3];
        out[0] = s / (float)((size_t)NROWS * (size_t)NCOLS);
    }
}

extern "C" void kernel_launch(void* const* d_in, const int* in_sizes, int n_in,
                              void* d_out, int out_size, void* d_ws, size_t ws_size,
                              hipStream_t stream) {
    const float* x = (const float*)d_in[0];
    const float* t = (const float*)d_in[1];
    float* partial = (float*)d_ws;  // NBLOCKS * 4 B = 32 KiB scratch

    biased_loss_lds<<<NBLOCKS, TPB, 0, stream>>>(x, t, partial);
    reduce_partials<<<1, 256, 0, stream>>>(partial, (float*)d_out, NBLOCKS);
}

// Round 7
// 253.619 us; speedup vs baseline: 1.1091x; 1.0932x over previous
//
#include <hip/hip_runtime.h>

#define NROWS 262144
#define NCOLS 128
#define TPB 256
#define WPB (TPB / 64)
#define NBLOCKS 4096
#define NWAVES (NBLOCKS * WPB)           // 16384 waves
#define NPAIRS (NROWS / 2)               // 131072
#define U 2                              // pairs batched per load phase
#define NBATCH (NPAIRS / (NWAVES * U))   // 4 batches per wave

typedef float floatx4 __attribute__((ext_vector_type(4)));

__device__ __forceinline__ floatx4 ntload4(const float* p)
{
    return __builtin_nontemporal_load((const floatx4*)p);
}

// R7: exact restore of the best-measured kernel (R1: 253.9 us, R0: 254.8 us).
// Session evidence (R3-R6): the op is pinned by a ~3.15 TB/s platform READ
// ceiling (same rate as the read side of m13's 6.29 TB/s copy; warm replays
// with FETCH~0 run equally slow, so caches don't lift it). NT loads are the
// one variant that reaches that ceiling (plain loads: 2.7 TB/s, +23 us total,
// R1-vs-R3 A/B). Structure changes (ballot argmax, row-per-thread,
// global_load_lds, forced MLP) were all neutral or worse -- do not touch.
__global__ __launch_bounds__(TPB) void biased_loss_partial(
    const float* __restrict__ x, const float* __restrict__ t,
    float* __restrict__ partial)
{
    const int lane = threadIdx.x & 63;
    const int waveInBlock = threadIdx.x >> 6;
    const int gw = blockIdx.x * WPB + waveInBlock;
    const int half = lane >> 5;
    const int sub  = lane & 31;
    const int c    = sub * 4;

    const size_t laneoff = (size_t)half * NCOLS + (size_t)c;

    float acc = 0.0f;

    floatx4 xv[U], tv[U];   // current batch
    floatx4 xn[U], tn[U];   // prefetched next batch

    // prologue: issue batch 0's loads
    {
        const int pbase = gw * U;
        #pragma unroll
        for (int u = 0; u < U; ++u) {
            const size_t base = (size_t)(2 * (pbase + u)) * NCOLS + laneoff;
            xv[u] = ntload4(x + base);
            tv[u] = ntload4(t + base);
        }
    }

    #pragma unroll
    for (int b = 0; b < NBATCH; ++b) {
        // issue batch b+1's loads before consuming batch b
        if (b + 1 < NBATCH) {
            const int pbase = ((b + 1) * NWAVES + gw) * U;
            #pragma unroll
            for (int u = 0; u < U; ++u) {
                const size_t base = (size_t)(2 * (pbase + u)) * NCOLS + laneoff;
                xn[u] = ntload4(x + base);
                tn[u] = ntload4(t + base);
            }
        }

        #pragma unroll
        for (int u = 0; u < U; ++u) {
            float bv = xv[u].x; int bi = c;
            if (xv[u].y > bv) { bv = xv[u].y; bi = c + 1; }
            if (xv[u].z > bv) { bv = xv[u].z; bi = c + 2; }
            if (xv[u].w > bv) { bv = xv[u].w; bi = c + 3; }

            // butterfly argmax across the 32-lane half (off<=16 stays in half)
            #pragma unroll
            for (int off = 16; off > 0; off >>= 1) {
                float ov = __shfl_xor(bv, off, 64);
                int   oi = __shfl_xor(bi, off, 64);
                if (ov > bv || (ov == bv && oi < bi)) { bv = ov; bi = oi; }
            }

            float t0 = __shfl(tv[u].x, half << 5, 64);
            const bool cond = (bi > 0) && (t0 == 0.0f);

            float c0 = fabsf(xv[u].x * tv[u].x);
            float c1 = fabsf(xv[u].y * tv[u].y);
            float c2 = fabsf(xv[u].z * tv[u].z);
            float c3 = fabsf(xv[u].w * tv[u].w);

            float s;
            if (cond) {
                s = (c     == bi ? c0 : 0.0f)
                  + (c + 1 == bi ? c1 : 0.0f)
                  + (c + 2 == bi ? c2 : 0.0f)
                  + (c + 3 == bi ? c3 : 0.0f);
            } else {
                s = (c0 + c1) + (c2 + c3);
            }
            acc += s;
        }

        if (b + 1 < NBATCH) {
            #pragma unroll
            for (int u = 0; u < U; ++u) { xv[u] = xn[u]; tv[u] = tn[u]; }
        }
    }

    // full-wave sum
    #pragma unroll
    for (int off = 32; off > 0; off >>= 1)
        acc += __shfl_xor(acc, off, 64);

    __shared__ float smem[WPB];
    if (lane == 0) smem[waveInBlock] = acc;
    __syncthreads();
    if (threadIdx.x == 0) {
        float bsum = 0.0f;
        #pragma unroll
        for (int w = 0; w < WPB; ++w) bsum += smem[w];
        partial[blockIdx.x] = bsum;
    }
}

__global__ __launch_bounds__(256) void reduce_partials(
    const float* __restrict__ partial, float* __restrict__ out, int n)
{
    float acc = 0.0f;
    for (int i = threadIdx.x; i < n; i += 256) acc += partial[i];
    #pragma unroll
    for (int off = 32; off > 0; off >>= 1)
        acc += __shfl_xor(acc, off, 64);
    __shared__ float smem[4];
    const int lane = threadIdx.x & 63, w = threadIdx.x >> 6;
    if (lane == 0) smem[w] = acc;
    __syncthreads();
    if (threadIdx.x == 0) {
        float s = smem[0] + smem[1] + smem[2] + smem[3];
        out[0] = s / (float)((size_t)NROWS * (size_t)NCOLS);
    }
}

extern "C" void kernel_launch(void* const* d_in, const int* in_sizes, int n_in,
                              void* d_out, int out_size, void* d_ws, size_t ws_size,
                              hipStream_t stream) {
    const float* x = (const float*)d_in[0];
    const float* t = (const float*)d_in[1];
    float* partial = (float*)d_ws;  // NBLOCKS * 4 B = 16 KiB scratch

    biased_loss_partial<<<NBLOCKS, TPB, 0, stream>>>(x, t, partial);
    reduce_partials<<<1, 256, 0, stream>>>(partial, (float*)d_out, NBLOCKS);
}